// Round 1
// baseline (6571.246 us; speedup 1.0000x reference)
//
#include <hip/hip_runtime.h>
#include <cstddef>
#include <cstdint>

#define VV 32000
#define EE 512
#define HH 1024
#define BB 128
#define SS 128
#define TT 15

// ---------------------------------------------------------------------------
// Generic split-K GEMM: C_partial[s] = A[128,K] @ W[N,K]^T  (row-major inputs)
// Tile: BM=128 (all rows), BN=128, BK=16. 256 threads, 8x8 microtile.
// Partials P layout: [KS][128][N]. Optional row-gather on A (embedding).
// ---------------------------------------------------------------------------
struct GemmDesc {
  const float* A;
  const float* W;
  const int* gather;   // null or [128] row indices into A
  float* P;            // [KS,128,N]
  int K;               // full K of A rows / W rows
  int kper;            // K-range per split (multiple of 16)
  int N;
};

__global__ __launch_bounds__(256) void gemm128_splitk(GemmDesc d) {
  __shared__ float As[16][128];
  __shared__ float Ws[16][128];
  const int tid = threadIdx.x;
  const int n0 = blockIdx.x * 128;
  const int sp = blockIdx.y;
  const int k0 = sp * d.kper;
  const int k1 = k0 + d.kper;
  const int tx = tid & 15, ty = tid >> 4;

  float acc[8][8];
#pragma unroll
  for (int i = 0; i < 8; ++i)
#pragma unroll
    for (int j = 0; j < 8; ++j) acc[i][j] = 0.f;

  for (int kk = k0; kk < k1; kk += 16) {
    __syncthreads();
#pragma unroll
    for (int jj = 0; jj < 2; ++jj) {
      int i = tid + jj * 256;          // 0..511
      int m = i >> 2;                  // 0..127
      int q = i & 3;                   // float4 chunk within 16 k's
      const float* Arow = d.gather ? (d.A + (size_t)d.gather[m] * d.K)
                                   : (d.A + (size_t)m * d.K);
      float4 va = *(const float4*)(Arow + kk + q * 4);
      As[q * 4 + 0][m] = va.x; As[q * 4 + 1][m] = va.y;
      As[q * 4 + 2][m] = va.z; As[q * 4 + 3][m] = va.w;
      const float* Wrow = d.W + (size_t)(n0 + m) * d.K;
      float4 vw = *(const float4*)(Wrow + kk + q * 4);
      Ws[q * 4 + 0][m] = vw.x; Ws[q * 4 + 1][m] = vw.y;
      Ws[q * 4 + 2][m] = vw.z; Ws[q * 4 + 3][m] = vw.w;
    }
    __syncthreads();
#pragma unroll
    for (int k = 0; k < 16; ++k) {
      float4 a0 = *(const float4*)&As[k][ty * 8];
      float4 a1 = *(const float4*)&As[k][ty * 8 + 4];
      float4 w0 = *(const float4*)&Ws[k][tx * 8];
      float4 w1 = *(const float4*)&Ws[k][tx * 8 + 4];
      float a[8] = {a0.x, a0.y, a0.z, a0.w, a1.x, a1.y, a1.z, a1.w};
      float w[8] = {w0.x, w0.y, w0.z, w0.w, w1.x, w1.y, w1.z, w1.w};
#pragma unroll
      for (int i = 0; i < 8; ++i)
#pragma unroll
        for (int j = 0; j < 8; ++j) acc[i][j] = fmaf(a[i], w[j], acc[i][j]);
    }
  }

  float* Pb = d.P + ((size_t)sp * 128) * d.N + n0;
#pragma unroll
  for (int i = 0; i < 8; ++i) {
    int m = ty * 8 + i;
    float4* dst = (float4*)(Pb + (size_t)m * d.N + tx * 8);
    dst[0] = make_float4(acc[i][0], acc[i][1], acc[i][2], acc[i][3]);
    dst[1] = make_float4(acc[i][4], acc[i][5], acc[i][6], acc[i][7]);
  }
}

// ---------------------------------------------------------------------------
// GRU gate combine: reduces split-K partials of gi and gh, applies gates.
// PyTorch GRU: r=sig(i_r+h_r) z=sig(i_z+h_z) n=tanh(i_n + r*h_n)
//              h' = (1-z)*n + z*h
// ---------------------------------------------------------------------------
__global__ __launch_bounds__(256) void gru_combine(const float* Pgi, const float* Pgh, int ns,
                                                   const float* bih, const float* bhh,
                                                   const float* hprev, float* hnew, float* cat) {
  int idx = blockIdx.x * 256 + threadIdx.x;     // 131072
  int b = idx >> 10, j = idx & 1023;
  float ir = 0, iz = 0, in_ = 0, hr = 0, hz = 0, hn = 0;
  for (int s2 = 0; s2 < ns; ++s2) {
    const float* p = Pgi + ((size_t)s2 * 128 + b) * 3072;
    ir += p[j]; iz += p[1024 + j]; in_ += p[2048 + j];
  }
  for (int s2 = 0; s2 < ns; ++s2) {
    const float* p = Pgh + ((size_t)s2 * 128 + b) * 3072;
    hr += p[j]; hz += p[1024 + j]; hn += p[2048 + j];
  }
  ir += bih[j]; iz += bih[1024 + j]; in_ += bih[2048 + j];
  hr += bhh[j]; hz += bhh[1024 + j]; hn += bhh[2048 + j];
  float r = 1.f / (1.f + expf(-(ir + hr)));
  float z = 1.f / (1.f + expf(-(iz + hz)));
  float n = tanhf(in_ + r * hn);
  float h = (1.f - z) * n + z * hprev[idx];
  hnew[idx] = h;
  if (cat) cat[(size_t)b * 2048 + j] = h;
}

// ---------------------------------------------------------------------------
// Attention: scores = enc[b,s,:]·h1[b,:], softmax over s, ctx into cat[:,H:].
// One block per batch row. 128 threads.
// ---------------------------------------------------------------------------
__global__ __launch_bounds__(128) void attn_kernel(const float* enc, const float* h1, float* cat) {
  __shared__ float hs[1024];
  __shared__ float sc[128];
  __shared__ float red[128];
  const int b = blockIdx.x, t = threadIdx.x;
  for (int i = t; i < 1024; i += 128) hs[i] = h1[(size_t)b * 1024 + i];
  __syncthreads();
  const float* er = enc + ((size_t)b * 128 + t) * 1024;
  float acc = 0.f;
  for (int h = 0; h < 1024; h += 4) {
    float4 e = *(const float4*)(er + h);
    acc += e.x * hs[h] + e.y * hs[h + 1] + e.z * hs[h + 2] + e.w * hs[h + 3];
  }
  red[t] = acc;
  __syncthreads();
  for (int off = 64; off > 0; off >>= 1) {
    if (t < off) red[t] = fmaxf(red[t], red[t + off]);
    __syncthreads();
  }
  float mx = red[0];
  __syncthreads();
  float w = expf(acc - mx);
  red[t] = w;
  __syncthreads();
  for (int off = 64; off > 0; off >>= 1) {
    if (t < off) red[t] += red[t + off];
    __syncthreads();
  }
  float zsum = red[0];
  sc[t] = w / zsum;
  __syncthreads();
  for (int rep = 0; rep < 8; ++rep) {
    int h = rep * 128 + t;
    float c = 0.f;
    for (int s2 = 0; s2 < 128; ++s2)
      c = fmaf(sc[s2], enc[((size_t)b * 128 + s2) * 1024 + h], c);
    cat[(size_t)b * 2048 + 1024 + h] = c;
  }
}

// W1 split-K reduce + tanh -> o [128,1024]
__global__ __launch_bounds__(256) void reduce_tanh(const float* P, float* o) {
  int idx = blockIdx.x * 256 + threadIdx.x;   // 131072
  int b = idx >> 10, j = idx & 1023;
  float s = 0.f;
  for (int k = 0; k < 16; ++k) s += P[((size_t)k * 128 + b) * 1024 + j];
  o[idx] = tanhf(s);
}

// ---------------------------------------------------------------------------
// Fused: logits = P0+P1+b2 -> d_out row; log_softmax in place; argmax -> tok.
// One block per batch row, 256 threads. First-index tie-break like jnp.argmax.
// ---------------------------------------------------------------------------
__global__ __launch_bounds__(256) void lsm_kernel(const float* P, const float* b2,
                                                  float* outbase, int tstep, int* tok) {
  const int b = blockIdx.x;
  const int t = threadIdx.x;
  float* orow = outbase + (size_t)b * (TT * VV) + (size_t)tstep * VV;
  const float* p0 = P + (size_t)b * VV;
  const float* p1 = P + (size_t)(128 + b) * VV;
  float mx = -3.4e38f; int mi = 0;
  for (int v = t; v < VV; v += 256) {
    float lg = p0[v] + p1[v] + b2[v];
    orow[v] = lg;
    if (lg > mx) { mx = lg; mi = v; }
  }
  __shared__ float rv[256]; __shared__ int ri[256]; __shared__ float sv[256];
  rv[t] = mx; ri[t] = mi;
  __syncthreads();
  for (int off = 128; off > 0; off >>= 1) {
    if (t < off) {
      if (rv[t + off] > rv[t] || (rv[t + off] == rv[t] && ri[t + off] < ri[t])) {
        rv[t] = rv[t + off]; ri[t] = ri[t + off];
      }
    }
    __syncthreads();
  }
  mx = rv[0];
  float se = 0.f;
  for (int v = t; v < VV; v += 256) se += expf(orow[v] - mx);
  sv[t] = se;
  __syncthreads();
  for (int off = 128; off > 0; off >>= 1) {
    if (t < off) sv[t] += sv[t + off];
    __syncthreads();
  }
  float lse = logf(sv[0]);
  for (int v = t; v < VV; v += 256) orow[v] = orow[v] - mx - lse;
  if (t == 0) tok[b] = ri[0];
}

__global__ __launch_bounds__(256) void init_kernel(const float* ehs, float* h0, float* h1, int* tok) {
  int idx = blockIdx.x * 256 + threadIdx.x;   // 131072
  h0[idx] = ehs[idx];
  h1[idx] = ehs[131072 + idx];
  if (idx < 128) tok[idx] = 0;
}

__global__ __launch_bounds__(256) void hfinal_kernel(const float* h0, const float* h1, float* out) {
  int idx = blockIdx.x * 256 + threadIdx.x;   // 131072
  out[61440000 + idx] = h0[idx];
  out[61440000 + 131072 + idx] = h1[idx];
}

extern "C" void kernel_launch(void* const* d_in, const int* in_sizes, int n_in,
                              void* d_out, int out_size, void* d_ws, size_t ws_size,
                              hipStream_t stream) {
  const float* ehs  = (const float*)d_in[1];   // [2,128,1024]
  const float* enc  = (const float*)d_in[2];   // [128,128,1024]
  const float* emb  = (const float*)d_in[3];   // [32000,512]
  const float* Wih0 = (const float*)d_in[4];
  const float* Whh0 = (const float*)d_in[5];
  const float* bih0 = (const float*)d_in[6];
  const float* bhh0 = (const float*)d_in[7];
  const float* Wih1 = (const float*)d_in[8];
  const float* Whh1 = (const float*)d_in[9];
  const float* bih1 = (const float*)d_in[10];
  const float* bhh1 = (const float*)d_in[11];
  const float* W1   = (const float*)d_in[12];  // [1024,2048]
  const float* W2   = (const float*)d_in[13];  // [32000,1024]
  const float* b2   = (const float*)d_in[14];  // [32000]
  float* out = (float*)d_out;

  // workspace layout (floats)
  float* w   = (float*)d_ws;
  int*   tok = (int*)d_ws;                 // 128 ints (256-float slot)
  float* h0  = w + 256;                    // 131072
  float* h1  = h0 + 131072;                // 131072
  float* cat = h1 + 131072;                // 262144
  float* o   = cat + 262144;               // 131072
  float* Sc  = o + 131072;                 // scratch region
  float* Pgi  = Sc;                        // 8*128*3072 = 3145728
  float* Pgh0 = Sc + 3145728;
  float* Pgh1 = Sc + 2 * 3145728;
  float* PW1  = Sc;                        // 16*128*1024 = 2097152 (reuse)
  float* PW2  = Sc + 2097152;              // 2*128*32000 = 8192000

  init_kernel<<<512, 256, 0, stream>>>(ehs, h0, h1, tok);

  for (int t = 0; t < TT; ++t) {
    // gi0 = emb[tok] @ Wih0^T   (K=512, KS=8)
    GemmDesc d_gi0 = {emb, Wih0, tok, Pgi, 512, 64, 3072};
    gemm128_splitk<<<dim3(24, 8), 256, 0, stream>>>(d_gi0);
    // gh0 = h0 @ Whh0^T   (K=1024, KS=8)
    GemmDesc d_gh0 = {h0, Whh0, nullptr, Pgh0, 1024, 128, 3072};
    gemm128_splitk<<<dim3(24, 8), 256, 0, stream>>>(d_gh0);
    // gh1 = h1 @ Whh1^T (reads OLD h1, so launch before combine1)
    GemmDesc d_gh1 = {h1, Whh1, nullptr, Pgh1, 1024, 128, 3072};
    gemm128_splitk<<<dim3(24, 8), 256, 0, stream>>>(d_gh1);
    // h0' = gates(gi0, gh0)
    gru_combine<<<512, 256, 0, stream>>>(Pgi, Pgh0, 8, bih0, bhh0, h0, h0, nullptr);
    // gi1 = h0' @ Wih1^T
    GemmDesc d_gi1 = {h0, Wih1, nullptr, Pgi, 1024, 128, 3072};
    gemm128_splitk<<<dim3(24, 8), 256, 0, stream>>>(d_gi1);
    // h1' = gates(gi1, gh1); also writes cat[:, :1024]
    gru_combine<<<512, 256, 0, stream>>>(Pgi, Pgh1, 8, bih1, bhh1, h1, h1, cat);
    // attention -> cat[:, 1024:]
    attn_kernel<<<128, 128, 0, stream>>>(enc, h1, cat);
    // W1: o = tanh(cat @ W1^T)   (K=2048, KS=16, N=1024)
    GemmDesc d_w1 = {cat, W1, nullptr, PW1, 2048, 128, 1024};
    gemm128_splitk<<<dim3(8, 16), 256, 0, stream>>>(d_w1);
    reduce_tanh<<<512, 256, 0, stream>>>(PW1, o);
    // W2: logits partials (K=1024, KS=2, N=32000)
    GemmDesc d_w2 = {o, W2, nullptr, PW2, 1024, 512, 32000};
    gemm128_splitk<<<dim3(250, 2), 256, 0, stream>>>(d_w2);
    // log_softmax + argmax, writes d_out[b, t, :], next token
    lsm_kernel<<<128, 256, 0, stream>>>(PW2, b2, out, t, tok);
  }

  hfinal_kernel<<<512, 256, 0, stream>>>(h0, h1, out);
}

// Round 2
// 2761.538 us; speedup vs baseline: 2.3796x; 2.3796x over previous
//
#include <hip/hip_runtime.h>
#include <cstddef>
#include <cstdint>

#define VV 32000
#define TT 15

typedef __bf16 bf16x8 __attribute__((ext_vector_type(8)));
typedef float f32x4 __attribute__((ext_vector_type(4)));
typedef short short4v __attribute__((ext_vector_type(4)));

__device__ __forceinline__ unsigned short f2bf(float x) {
  unsigned u = __builtin_bit_cast(unsigned, x);
  unsigned r = u + 0x7FFFu + ((u >> 16) & 1u);
  return (unsigned short)(r >> 16);
}
__device__ __forceinline__ float bf2f(unsigned short h) {
  unsigned u = ((unsigned)h) << 16;
  return __builtin_bit_cast(float, u);
}

__device__ __forceinline__ void gload16(void* lds, const void* g) {
  __builtin_amdgcn_global_load_lds((const __attribute__((address_space(1))) void*)g,
                                   (__attribute__((address_space(3))) void*)lds, 16, 0, 0);
}

// ---------------------------------------------------------------------------
// MFMA GEMM: O = A[128,K] @ W[N,K]^T via split-bf16 (hi+lo), 3 MFMAs/pair.
// A is pre-packed: hi plane [128][K] shorts, lo plane at +128*K.
// W: if WPK, packed hi plane [N][K] shorts + lo at +N*K; else fp32 [N][K].
// Block: 256 thr, tile BM=128 x BN=64 x BK=32. 4 waves in 2x2 grid.
// Split-K partials (or direct out with bias when nsplits==1).
// ---------------------------------------------------------------------------
struct MD {
  const short* Ahi;
  const void* W;
  float* P;
  const float* bias;
  int K;
  int kper;
  int N;
  int rowStride;
  int spStride;
};
struct G3 { MD d[3]; int y0, y01; };

template<bool WPK>
__global__ __launch_bounds__(256) void gemm_mfma(G3 g) {
  const int di = (blockIdx.y < (unsigned)g.y0) ? 0 : (blockIdx.y < (unsigned)g.y01 ? 1 : 2);
  const int sp = blockIdx.y - (di == 0 ? 0 : (di == 1 ? g.y0 : g.y01));
  const MD d = g.d[di];
  const int tid = threadIdx.x;
  const int l = tid & 63, w = tid >> 6;
  const int n0 = blockIdx.x * 64;
  if (n0 >= d.N) return;

  __shared__ __align__(16) short Ah[4 * 128 * 8];
  __shared__ __align__(16) short Al[4 * 128 * 8];
  __shared__ __align__(16) short Wh[4 * 64 * 8];
  __shared__ __align__(16) short Wl[4 * 64 * 8];

  const int wm = w & 1, wn = w >> 1;
  f32x4 acc[4][2];
#pragma unroll
  for (int i = 0; i < 4; ++i)
#pragma unroll
    for (int j = 0; j < 2; ++j) acc[i][j] = (f32x4){0.f, 0.f, 0.f, 0.f};

  const short* Alo = d.Ahi + (size_t)128 * d.K;
  const int k0 = sp * d.kper, k1 = k0 + d.kper;

  // A chunk ids
  const int c0 = tid, c1 = tid + 256;
  const int m0 = c0 & 127, kb0 = c0 >> 7;
  const int m1 = c1 & 127, kb1 = c1 >> 7;
  // W chunk id (one per thread)
  const int wn_c = tid & 63, wkb = tid >> 6;

  for (int kk = k0; kk < k1; kk += 32) {
    __syncthreads();
    gload16(Ah + (size_t)(w * 64) * 8,        d.Ahi + (size_t)m0 * d.K + kk + kb0 * 8);
    gload16(Ah + (size_t)(256 + w * 64) * 8,  d.Ahi + (size_t)m1 * d.K + kk + kb1 * 8);
    gload16(Al + (size_t)(w * 64) * 8,        Alo + (size_t)m0 * d.K + kk + kb0 * 8);
    gload16(Al + (size_t)(256 + w * 64) * 8,  Alo + (size_t)m1 * d.K + kk + kb1 * 8);
    if constexpr (WPK) {
      const short* Whi = (const short*)d.W;
      const short* Wlo2 = Whi + (size_t)d.N * d.K;
      gload16(Wh + (size_t)(w * 64) * 8, Whi + (size_t)(n0 + wn_c) * d.K + kk + wkb * 8);
      gload16(Wl + (size_t)(w * 64) * 8, Wlo2 + (size_t)(n0 + wn_c) * d.K + kk + wkb * 8);
    } else {
      const float* Wf = (const float*)d.W;
      const float* src = Wf + (size_t)(n0 + wn_c) * d.K + kk + wkb * 8;
      float4 v0 = *(const float4*)(src);
      float4 v1 = *(const float4*)(src + 4);
      float vv[8] = {v0.x, v0.y, v0.z, v0.w, v1.x, v1.y, v1.z, v1.w};
      short hi8[8], lo8[8];
#pragma unroll
      for (int e = 0; e < 8; ++e) {
        unsigned short h = f2bf(vv[e]);
        hi8[e] = (short)h;
        lo8[e] = (short)f2bf(vv[e] - bf2f(h));
      }
      *(short4v*)(Wh + (size_t)tid * 8)     = *(short4v*)hi8;
      *(short4v*)(Wh + (size_t)tid * 8 + 4) = *(short4v*)(hi8 + 4);
      *(short4v*)(Wl + (size_t)tid * 8)     = *(short4v*)lo8;
      *(short4v*)(Wl + (size_t)tid * 8 + 4) = *(short4v*)(lo8 + 4);
    }
    __syncthreads();

    const int kq = l >> 4;
    const int mb = wm * 64 + (l & 15);
    const int nb = wn * 32 + (l & 15);
    bf16x8 a_h[4], a_l[4], w_h[2], w_l[2];
#pragma unroll
    for (int i = 0; i < 4; ++i) {
      int off = (kq * 128 + mb + i * 16) * 8;
      a_h[i] = *(const bf16x8*)(Ah + off);
      a_l[i] = *(const bf16x8*)(Al + off);
    }
#pragma unroll
    for (int j = 0; j < 2; ++j) {
      int off = (kq * 64 + nb + j * 16) * 8;
      w_h[j] = *(const bf16x8*)(Wh + off);
      w_l[j] = *(const bf16x8*)(Wl + off);
    }
#pragma unroll
    for (int i = 0; i < 4; ++i)
#pragma unroll
      for (int j = 0; j < 2; ++j) {
        acc[i][j] = __builtin_amdgcn_mfma_f32_16x16x32_bf16(a_h[i], w_h[j], acc[i][j], 0, 0, 0);
        acc[i][j] = __builtin_amdgcn_mfma_f32_16x16x32_bf16(a_h[i], w_l[j], acc[i][j], 0, 0, 0);
        acc[i][j] = __builtin_amdgcn_mfma_f32_16x16x32_bf16(a_l[i], w_h[j], acc[i][j], 0, 0, 0);
      }
  }

  float* base = d.P + (size_t)sp * d.spStride;
#pragma unroll
  for (int i = 0; i < 4; ++i) {
    int m = wm * 64 + i * 16 + (l >> 4) * 4;
#pragma unroll
    for (int j = 0; j < 2; ++j) {
      int n = n0 + wn * 32 + j * 16 + (l & 15);
      float bv = d.bias ? d.bias[n] : 0.f;
#pragma unroll
      for (int r = 0; r < 4; ++r)
        base[(size_t)(m + r) * d.rowStride + n] = acc[i][j][r] + bv;
    }
  }
}

// ---------------------------------------------------------------------------
// Weight pre-split: fp32 -> bf16 hi plane + lo plane.
// ---------------------------------------------------------------------------
__global__ __launch_bounds__(256) void pack_split(const float* __restrict__ src,
                                                  short* __restrict__ hi, int n4) {
  short* lo = hi + (size_t)n4 * 4;
  int stride = gridDim.x * 256;
  for (int i = blockIdx.x * 256 + threadIdx.x; i < n4; i += stride) {
    float4 v = ((const float4*)src)[i];
    float vv[4] = {v.x, v.y, v.z, v.w};
    short h4[4], l4[4];
#pragma unroll
    for (int e = 0; e < 4; ++e) {
      unsigned short h = f2bf(vv[e]);
      h4[e] = (short)h;
      l4[e] = (short)f2bf(vv[e] - bf2f(h));
    }
    ((short4v*)hi)[i] = *(short4v*)h4;
    ((short4v*)lo)[i] = *(short4v*)l4;
  }
}

// Embedding gather + split for current tokens: x_pk[2][128][512]
__global__ __launch_bounds__(128) void xpk_kernel(const float* __restrict__ emb,
                                                  const int* __restrict__ tok,
                                                  short* __restrict__ xpk) {
  const int b = blockIdx.x, t = threadIdx.x;
  const float* row = emb + (size_t)tok[b] * 512;
  float4 v = ((const float4*)row)[t];
  float vv[4] = {v.x, v.y, v.z, v.w};
  int base = b * 512 + t * 4;
#pragma unroll
  for (int e = 0; e < 4; ++e) {
    unsigned short h = f2bf(vv[e]);
    xpk[base + e] = (short)h;
    xpk[65536 + base + e] = (short)f2bf(vv[e] - bf2f(h));
  }
}

// ---------------------------------------------------------------------------
// GRU gate combine (split-K reduce + gates) -> h fp32 + packed (+ cat packed)
// ---------------------------------------------------------------------------
__global__ __launch_bounds__(256) void gru_combine(const float* __restrict__ Pgi, int ngi,
                                                   const float* __restrict__ Pgh, int ngh,
                                                   const float* __restrict__ bih,
                                                   const float* __restrict__ bhh,
                                                   const float* __restrict__ hprev,
                                                   float* __restrict__ hnewf,
                                                   short* __restrict__ hpk,
                                                   short* __restrict__ catpk) {
  int idx = blockIdx.x * 256 + threadIdx.x;  // 131072
  int b = idx >> 10, j = idx & 1023;
  float ir = 0, iz = 0, in_ = 0, hr = 0, hz = 0, hn = 0;
  for (int s2 = 0; s2 < ngi; ++s2) {
    const float* p = Pgi + ((size_t)s2 * 128 + b) * 3072;
    ir += p[j]; iz += p[1024 + j]; in_ += p[2048 + j];
  }
  for (int s2 = 0; s2 < ngh; ++s2) {
    const float* p = Pgh + ((size_t)s2 * 128 + b) * 3072;
    hr += p[j]; hz += p[1024 + j]; hn += p[2048 + j];
  }
  ir += bih[j]; iz += bih[1024 + j]; in_ += bih[2048 + j];
  hr += bhh[j]; hz += bhh[1024 + j]; hn += bhh[2048 + j];
  float r = 1.f / (1.f + expf(-(ir + hr)));
  float z = 1.f / (1.f + expf(-(iz + hz)));
  float n = tanhf(in_ + r * hn);
  float h = (1.f - z) * n + z * hprev[idx];
  hnewf[idx] = h;
  unsigned short hh = f2bf(h);
  unsigned short hl = f2bf(h - bf2f(hh));
  hpk[idx] = (short)hh;
  hpk[131072 + idx] = (short)hl;
  if (catpk) {
    catpk[(size_t)b * 2048 + j] = (short)hh;
    catpk[262144 + (size_t)b * 2048 + j] = (short)hl;
  }
}

// ---------------------------------------------------------------------------
// Attention: scores, softmax, ctx -> catpk[:, 1024:] (packed)
// ---------------------------------------------------------------------------
__global__ __launch_bounds__(512) void attn_kernel(const float* __restrict__ enc,
                                                   const float* __restrict__ h1f,
                                                   short* __restrict__ catpk) {
  __shared__ float hs[1024];
  __shared__ float sc[128];
  __shared__ float red[128];
  const int b = blockIdx.x, t = threadIdx.x;
  for (int i = t; i < 1024; i += 512) hs[i] = h1f[(size_t)b * 1024 + i];
  __syncthreads();
  const int s = t >> 2, seg = t & 3;
  const float* er = enc + ((size_t)b * 128 + s) * 1024;
  float a = 0.f;
#pragma unroll 4
  for (int h = 0; h < 1024; h += 16) {
    float4 e = *(const float4*)(er + h + seg * 4);
    const float* hp = hs + h + seg * 4;
    a += e.x * hp[0] + e.y * hp[1] + e.z * hp[2] + e.w * hp[3];
  }
  a += __shfl_xor(a, 1);
  a += __shfl_xor(a, 2);
  if (seg == 0) sc[s] = a;
  __syncthreads();
  if (t < 128) red[t] = sc[t];
  __syncthreads();
  for (int off = 64; off > 0; off >>= 1) {
    if (t < off) red[t] = fmaxf(red[t], red[t + off]);
    __syncthreads();
  }
  float mx = red[0];
  __syncthreads();
  if (t < 128) sc[t] = expf(sc[t] - mx);
  __syncthreads();
  if (t < 128) red[t] = sc[t];
  __syncthreads();
  for (int off = 64; off > 0; off >>= 1) {
    if (t < off) red[t] += red[t + off];
    __syncthreads();
  }
  float inv = 1.f / red[0];
  __syncthreads();
  if (t < 128) sc[t] *= inv;
  __syncthreads();
#pragma unroll
  for (int rep = 0; rep < 2; ++rep) {
    int j = rep * 512 + t;
    float c = 0.f;
    for (int s2 = 0; s2 < 128; ++s2)
      c = fmaf(sc[s2], enc[((size_t)b * 128 + s2) * 1024 + j], c);
    unsigned short ch = f2bf(c);
    unsigned short cl = f2bf(c - bf2f(ch));
    catpk[(size_t)b * 2048 + 1024 + j] = (short)ch;
    catpk[262144 + (size_t)b * 2048 + 1024 + j] = (short)cl;
  }
}

// W1 split-K reduce + tanh -> o packed
__global__ __launch_bounds__(256) void reduce_tanh(const float* __restrict__ P,
                                                   short* __restrict__ opk) {
  int idx = blockIdx.x * 256 + threadIdx.x;  // 131072
  int b = idx >> 10, j = idx & 1023;
  float s = 0.f;
  for (int k = 0; k < 8; ++k) s += P[((size_t)k * 128 + b) * 1024 + j];
  float o = tanhf(s);
  unsigned short h = f2bf(o);
  opk[idx] = (short)h;
  opk[131072 + idx] = (short)f2bf(o - bf2f(h));
}

// log-softmax in place on d_out row + argmax -> tok
__global__ __launch_bounds__(1024) void lsm_kernel(float* __restrict__ outbase, int tstep,
                                                   int* __restrict__ tok) {
  __shared__ float rv[1024];
  __shared__ int ri[1024];
  const int b = blockIdx.x, t = threadIdx.x;
  float* orow = outbase + (size_t)b * 480000 + (size_t)tstep * 32000;
  float mx = -3.4e38f;
  int mi = 0x7fffffff;
  for (int v = t; v < 32000; v += 1024) {
    float lg = orow[v];
    if (lg > mx) { mx = lg; mi = v; }
  }
  rv[t] = mx; ri[t] = mi;
  __syncthreads();
  for (int off = 512; off > 0; off >>= 1) {
    if (t < off) {
      float ov = rv[t + off]; int oi = ri[t + off];
      if (ov > rv[t] || (ov == rv[t] && oi < ri[t])) { rv[t] = ov; ri[t] = oi; }
    }
    __syncthreads();
  }
  mx = rv[0];
  if (t == 0) tok[b] = ri[0];
  __syncthreads();
  float se = 0.f;
  for (int v = t; v < 32000; v += 1024) se += expf(orow[v] - mx);
  rv[t] = se;
  __syncthreads();
  for (int off = 512; off > 0; off >>= 1) {
    if (t < off) rv[t] += rv[t + off];
    __syncthreads();
  }
  float sub = mx + logf(rv[0]);
  for (int v = t; v < 32000; v += 1024) orow[v] -= sub;
}

__global__ __launch_bounds__(256) void init_kernel(const float* __restrict__ ehs,
                                                   float* __restrict__ h0f, float* __restrict__ h1f,
                                                   short* __restrict__ h0pk, short* __restrict__ h1pk,
                                                   int* __restrict__ tok) {
  int idx = blockIdx.x * 256 + threadIdx.x;  // 131072
  float a = ehs[idx], c = ehs[131072 + idx];
  h0f[idx] = a; h1f[idx] = c;
  unsigned short ah = f2bf(a);
  h0pk[idx] = (short)ah; h0pk[131072 + idx] = (short)f2bf(a - bf2f(ah));
  unsigned short ch = f2bf(c);
  h1pk[idx] = (short)ch; h1pk[131072 + idx] = (short)f2bf(c - bf2f(ch));
  if (idx < 128) tok[idx] = 0;
}

__global__ __launch_bounds__(256) void hfinal_kernel(const float* __restrict__ h0f,
                                                     const float* __restrict__ h1f,
                                                     float* __restrict__ out) {
  int idx = blockIdx.x * 256 + threadIdx.x;  // 131072
  out[61440000 + idx] = h0f[idx];
  out[61440000 + 131072 + idx] = h1f[idx];
}

extern "C" void kernel_launch(void* const* d_in, const int* in_sizes, int n_in,
                              void* d_out, int out_size, void* d_ws, size_t ws_size,
                              hipStream_t stream) {
  const float* ehs  = (const float*)d_in[1];
  const float* enc  = (const float*)d_in[2];
  const float* emb  = (const float*)d_in[3];
  const float* Wih0 = (const float*)d_in[4];
  const float* Whh0 = (const float*)d_in[5];
  const float* bih0 = (const float*)d_in[6];
  const float* bhh0 = (const float*)d_in[7];
  const float* Wih1 = (const float*)d_in[8];
  const float* Whh1 = (const float*)d_in[9];
  const float* bih1 = (const float*)d_in[10];
  const float* bhh1 = (const float*)d_in[11];
  const float* W1   = (const float*)d_in[12];
  const float* W2   = (const float*)d_in[13];
  const float* b2   = (const float*)d_in[14];
  float* out = (float*)d_out;

  char* p = (char*)d_ws;
  auto alloc = [&](size_t sz) -> char* {
    char* r = p;
    p += (sz + 255) & ~(size_t)255;
    return r;
  };
  int*   tok   = (int*)alloc(512);
  float* h0f   = (float*)alloc(524288);
  float* h1f   = (float*)alloc(524288);
  short* h0pk  = (short*)alloc(524288);
  short* h1pk  = (short*)alloc(524288);
  short* xpk   = (short*)alloc(262144);
  short* catpk = (short*)alloc(1048576);
  short* opk   = (short*)alloc(524288);
  float* Pgi   = (float*)alloc(6291456);
  float* Pgh0  = (float*)alloc(6291456);
  float* Pgh1  = (float*)alloc(6291456);
  float* PW1   = (float*)alloc(4194304);
  size_t core_end = (size_t)(p - (char*)d_ws);

  const size_t W2PK_B = 131072000, GRUPK_B = 52428800;
  bool packW2  = ws_size >= core_end + W2PK_B;
  bool packGRU = ws_size >= core_end + W2PK_B + GRUPK_B;
  short* W2pk = packW2 ? (short*)alloc(W2PK_B) : nullptr;
  short *W1pk = nullptr, *Wih0pk = nullptr, *Whh0pk = nullptr, *Wih1pk = nullptr, *Whh1pk = nullptr;
  if (packGRU) {
    W1pk   = (short*)alloc(8388608);
    Wih0pk = (short*)alloc(6291456);
    Whh0pk = (short*)alloc(12582912);
    Wih1pk = (short*)alloc(12582912);
    Whh1pk = (short*)alloc(12582912);
  }

  if (packW2)
    pack_split<<<4096, 256, 0, stream>>>(W2, W2pk, 32000 * 1024 / 4);
  if (packGRU) {
    pack_split<<<2048, 256, 0, stream>>>(W1, W1pk, 1024 * 2048 / 4);
    pack_split<<<1536, 256, 0, stream>>>(Wih0, Wih0pk, 3072 * 512 / 4);
    pack_split<<<2048, 256, 0, stream>>>(Whh0, Whh0pk, 3072 * 1024 / 4);
    pack_split<<<2048, 256, 0, stream>>>(Wih1, Wih1pk, 3072 * 1024 / 4);
    pack_split<<<2048, 256, 0, stream>>>(Whh1, Whh1pk, 3072 * 1024 / 4);
  }

  init_kernel<<<512, 256, 0, stream>>>(ehs, h0f, h1f, h0pk, h1pk, tok);

  auto launch1 = [&](MD md, int nbx, int nsp, bool wpk) {
    G3 g; g.d[0] = md; g.d[1] = md; g.d[2] = md;
    g.y0 = 0x7fffffff; g.y01 = 0x7fffffff;
    if (wpk) gemm_mfma<true><<<dim3(nbx, nsp), 256, 0, stream>>>(g);
    else     gemm_mfma<false><<<dim3(nbx, nsp), 256, 0, stream>>>(g);
  };

  for (int t = 0; t < TT; ++t) {
    xpk_kernel<<<128, 128, 0, stream>>>(emb, tok, xpk);

    // fused gi0 + gh0 + gh1
    {
      G3 g;
      g.d[0] = MD{xpk,  packGRU ? (const void*)Wih0pk : (const void*)Wih0, Pgi,  nullptr, 512,  256, 3072, 3072, 393216};
      g.d[1] = MD{h0pk, packGRU ? (const void*)Whh0pk : (const void*)Whh0, Pgh0, nullptr, 1024, 256, 3072, 3072, 393216};
      g.d[2] = MD{h1pk, packGRU ? (const void*)Whh1pk : (const void*)Whh1, Pgh1, nullptr, 1024, 256, 3072, 3072, 393216};
      g.y0 = 2; g.y01 = 6;
      if (packGRU) gemm_mfma<true><<<dim3(48, 10), 256, 0, stream>>>(g);
      else         gemm_mfma<false><<<dim3(48, 10), 256, 0, stream>>>(g);
    }
    gru_combine<<<512, 256, 0, stream>>>(Pgi, 2, Pgh0, 4, bih0, bhh0, h0f, h0f, h0pk, nullptr);

    launch1(MD{h0pk, packGRU ? (const void*)Wih1pk : (const void*)Wih1, Pgi, nullptr, 1024, 256, 3072, 3072, 393216},
            48, 4, packGRU);
    gru_combine<<<512, 256, 0, stream>>>(Pgi, 4, Pgh1, 4, bih1, bhh1, h1f, h1f, h1pk, catpk);

    attn_kernel<<<128, 512, 0, stream>>>(enc, h1f, catpk);

    launch1(MD{catpk, packGRU ? (const void*)W1pk : (const void*)W1, PW1, nullptr, 2048, 256, 1024, 1024, 131072},
            16, 8, packGRU);
    reduce_tanh<<<512, 256, 0, stream>>>(PW1, opk);

    launch1(MD{opk, packW2 ? (const void*)W2pk : (const void*)W2, out + (size_t)t * VV, b2, 1024, 1024, 32000, TT * VV, 0},
            500, 1, packW2);
    lsm_kernel<<<128, 1024, 0, stream>>>(out, t, tok);
  }

  hfinal_kernel<<<512, 256, 0, stream>>>(h0f, h1f, out);
}